// Round 1
// baseline (684.902 us; speedup 1.0000x reference)
//
#include <hip/hip_runtime.h>
#include <stdint.h>

typedef unsigned short u16;
typedef unsigned int   u32;
typedef __attribute__((ext_vector_type(8))) __bf16 bf16x8;
typedef __attribute__((ext_vector_type(4))) float  f32x4;

#define NB  64
#define NQ  784
#define NK  196
#define NKP 208      // nk padded to 13*16
#define DM  512
#define S2S 212      // padded LDS stride (floats) for score rows

static __device__ inline u16 f2bf(float f) {
  u32 u = __float_as_uint(f);
  u32 r = (u + 0x7fffu + ((u >> 16) & 1u)) >> 16;
  return (u16)r;
}

union BU { bf16x8 v; u16 s[8]; uint4 u; };

static __device__ inline bf16x8 ld8(const u16* p) {
  return *reinterpret_cast<const bf16x8*>(p);
}
static __device__ inline bf16x8 zero8() {
  BU z; z.u = make_uint4(0u, 0u, 0u, 0u); return z.v;
}
static __device__ inline bf16x8 cvt8(const float* p) {
  float4 a = *reinterpret_cast<const float4*>(p);
  float4 b = *reinterpret_cast<const float4*>(p + 4);
  BU r;
  r.s[0] = f2bf(a.x); r.s[1] = f2bf(a.y); r.s[2] = f2bf(a.z); r.s[3] = f2bf(a.w);
  r.s[4] = f2bf(b.x); r.s[5] = f2bf(b.y); r.s[6] = f2bf(b.z); r.s[7] = f2bf(b.w);
  return r.v;
}
static __device__ inline f32x4 mfma16(bf16x8 a, bf16x8 b, f32x4 c) {
  return __builtin_amdgcn_mfma_f32_16x16x32_bf16(a, b, c, 0, 0, 0);
}

// ---------------- fp32 -> bf16 weight conversion ----------------
__global__ __launch_bounds__(256) void cvt_kernel(const float* __restrict__ in,
                                                  u16* __restrict__ out, int n) {
  int i = (blockIdx.x * 256 + threadIdx.x) * 4;
  if (i + 3 < n) {
    float4 f = *reinterpret_cast<const float4*>(in + i);
    ushort4 o;
    o.x = f2bf(f.x); o.y = f2bf(f.y); o.z = f2bf(f.z); o.w = f2bf(f.w);
    *reinterpret_cast<ushort4*>(out + i) = o;
  }
}

// ---------------- spatial-reduce + LayerNorm -> bf16 x_ln [64][208][512] ----------------
__global__ __launch_bounds__(256) void ln_kernel(const float* __restrict__ q,
                                                 const float* __restrict__ sr_w,
                                                 const float* __restrict__ sr_b,
                                                 const float* __restrict__ ln_w,
                                                 const float* __restrict__ ln_b,
                                                 u16* __restrict__ xln) {
  int wave = blockIdx.x * 4 + (threadIdx.x >> 6);
  int lane = threadIdx.x & 63;
  if (wave >= NB * NKP) return;
  int b = wave / NKP, n = wave % NKP;
  u16* outp = xln + ((size_t)(b * NKP + n)) * DM;
  if (n >= NK) {  // zero pad row
    *reinterpret_cast<uint4*>(outp + lane * 8) = make_uint4(0u, 0u, 0u, 0u);
    return;
  }
  int src_n = (2 * (n / 14)) * 28 + 2 * (n % 14);
  const float* row = q + ((size_t)(b * NQ + src_n)) * DM;
  int c0 = lane * 4, c1 = 256 + lane * 4;
  float4 x0 = *reinterpret_cast<const float4*>(row + c0);
  float4 x1 = *reinterpret_cast<const float4*>(row + c1);
  float4 w0 = *reinterpret_cast<const float4*>(sr_w + c0);
  float4 w1 = *reinterpret_cast<const float4*>(sr_w + c1);
  float4 s0 = *reinterpret_cast<const float4*>(sr_b + c0);
  float4 s1 = *reinterpret_cast<const float4*>(sr_b + c1);
  float y[8];
  y[0] = x0.x * w0.x + s0.x; y[1] = x0.y * w0.y + s0.y;
  y[2] = x0.z * w0.z + s0.z; y[3] = x0.w * w0.w + s0.w;
  y[4] = x1.x * w1.x + s1.x; y[5] = x1.y * w1.y + s1.y;
  y[6] = x1.z * w1.z + s1.z; y[7] = x1.w * w1.w + s1.w;
  float s = 0.f, ss = 0.f;
  #pragma unroll
  for (int i = 0; i < 8; i++) { s += y[i]; ss += y[i] * y[i]; }
  #pragma unroll
  for (int off = 1; off < 64; off <<= 1) {
    s += __shfl_xor(s, off); ss += __shfl_xor(ss, off);
  }
  float mu = s * (1.f / 512.f);
  float var = ss * (1.f / 512.f) - mu * mu;
  float rs = rsqrtf(var + 1e-5f);
  float4 lw0 = *reinterpret_cast<const float4*>(ln_w + c0);
  float4 lw1 = *reinterpret_cast<const float4*>(ln_w + c1);
  float4 lb0 = *reinterpret_cast<const float4*>(ln_b + c0);
  float4 lb1 = *reinterpret_cast<const float4*>(ln_b + c1);
  ushort4 o0, o1;
  o0.x = f2bf((y[0] - mu) * rs * lw0.x + lb0.x);
  o0.y = f2bf((y[1] - mu) * rs * lw0.y + lb0.y);
  o0.z = f2bf((y[2] - mu) * rs * lw0.z + lb0.z);
  o0.w = f2bf((y[3] - mu) * rs * lw0.w + lb0.w);
  o1.x = f2bf((y[4] - mu) * rs * lw1.x + lb1.x);
  o1.y = f2bf((y[5] - mu) * rs * lw1.y + lb1.y);
  o1.z = f2bf((y[6] - mu) * rs * lw1.z + lb1.z);
  o1.w = f2bf((y[7] - mu) * rs * lw1.w + lb1.w);
  *reinterpret_cast<ushort4*>(outp + c0) = o0;
  *reinterpret_cast<ushort4*>(outp + c1) = o1;
}

// ---------------- generic no-LDS MFMA GEMM: C[M,512] = A[M,512] * W[512,512]^T + bias ----
// AMODE: 0 = bf16 A, 1 = fp32 A (convert on load)
// OMODE: 0 = bf16 C [row][col], 1 = fp32 C [row][col], 2 = bf16 VT: C[b][col][row%208]
template <int AMODE, int OMODE>
__global__ __launch_bounds__(256) void gemm_kernel(const void* __restrict__ Aptr,
                                                   const u16* __restrict__ Bw,
                                                   const float* __restrict__ bias,
                                                   void* __restrict__ Cptr) {
  int nt = blockIdx.x;   // 0..3  (128 cols each)
  int mt = blockIdx.y;
  int wv = threadIdx.x >> 6, lane = threadIdx.x & 63;
  int lr = lane & 15, lg = lane >> 4;
  int row0 = mt * 128 + wv * 32;
  int col0 = nt * 128;
  f32x4 acc[2][8] = {};
  for (int kk = 0; kk < 512; kk += 32) {
    int kof = kk + lg * 8;
    bf16x8 a0, a1;
    if (AMODE == 0) {
      const u16* ap = (const u16*)Aptr;
      a0 = ld8(ap + (size_t)(row0 + lr) * DM + kof);
      a1 = ld8(ap + (size_t)(row0 + 16 + lr) * DM + kof);
    } else {
      const float* ap = (const float*)Aptr;
      a0 = cvt8(ap + (size_t)(row0 + lr) * DM + kof);
      a1 = cvt8(ap + (size_t)(row0 + 16 + lr) * DM + kof);
    }
    #pragma unroll
    for (int j = 0; j < 8; j++) {
      bf16x8 bfr = ld8(Bw + (size_t)(col0 + j * 16 + lr) * DM + kof);
      acc[0][j] = mfma16(a0, bfr, acc[0][j]);
      acc[1][j] = mfma16(a1, bfr, acc[1][j]);
    }
  }
  #pragma unroll
  for (int mi = 0; mi < 2; mi++) {
    #pragma unroll
    for (int j = 0; j < 8; j++) {
      int col = col0 + j * 16 + lr;
      float bs = bias[col];
      #pragma unroll
      for (int r = 0; r < 4; r++) {
        int row = row0 + mi * 16 + lg * 4 + r;
        float v = acc[mi][j][r] + bs;
        if (OMODE == 0) {
          ((u16*)Cptr)[(size_t)row * DM + col] = f2bf(v);
        } else if (OMODE == 1) {
          ((float*)Cptr)[(size_t)row * DM + col] = v;
        } else {
          int b = row / NKP, kr = row % NKP;
          ((u16*)Cptr)[((size_t)b * DM + col) * NKP + kr] = f2bf(v);
        }
      }
    }
  }
}

// ---------------- fused scores + head-mix + softmax + PV ----------------
// grid (49, 64); 256 threads (4 waves); dynamic LDS.
#define S2_BYTES   (128 * S2S * 4)            // 108544
#define P_OFF      S2_BYTES
#define P_BYTES    (128 * NKP * 2)            // 53248
#define RSUM_OFF   (P_OFF + P_BYTES)          // 161792
#define TW_OFF     (RSUM_OFF + 512)           // 162304
#define TB_OFF     (TW_OFF + 256)             // 162560
#define ATTN_SHMEM (TB_OFF + 32)              // 162592

__global__ __launch_bounds__(256) void attn_kernel(const u16* __restrict__ Q,
                                                   const u16* __restrict__ K,
                                                   const u16* __restrict__ VT,
                                                   const float* __restrict__ tw,
                                                   const float* __restrict__ tb,
                                                   u16* __restrict__ Oat) {
  extern __shared__ char lds[];
  float* s2 = (float*)lds;                       // [8g][16q] rows, stride S2S floats
  u16* pb = (u16*)(lds + P_OFF);                 // [8g][16q][208] bf16
  float* rowsum = (float*)(lds + RSUM_OFF);      // [128]
  float* twl = (float*)(lds + TW_OFF);           // [64]
  float* tbl = (float*)(lds + TB_OFF);           // [8]

  int qt = blockIdx.x, b = blockIdx.y;
  int tid = threadIdx.x, wv = tid >> 6, lane = tid & 63;
  int lr = lane & 15, lg = lane >> 4;
  int q0 = qt * 16;

  if (tid < 64) twl[tid] = tw[tid];
  if (tid >= 64 && tid < 72) tbl[tid - 64] = tb[tid - 64];
  __syncthreads();

  const u16* Qb = Q + ((size_t)(b * NQ + q0)) * DM;
  const u16* Kb = K + (size_t)b * NKP * DM;
  const u16* VTb = VT + (size_t)b * DM * NKP;

  // hoist Q fragments for all 8 heads (row = lr, contraction d = lg*8..)
  bf16x8 qf[8][2];
  #pragma unroll
  for (int h = 0; h < 8; h++) {
    qf[h][0] = ld8(Qb + (size_t)lr * DM + h * 64 + lg * 8);
    qf[h][1] = ld8(Qb + (size_t)lr * DM + h * 64 + 32 + lg * 8);
  }

  // Phase A: scores for all heads, mix in-register, write mixed fp32 scores
  for (int kt = wv; kt < 13; kt += 4) {
    int k0 = kt * 16;
    f32x4 acc[8];
    #pragma unroll
    for (int h = 0; h < 8; h++) {
      acc[h] = (f32x4){0.f, 0.f, 0.f, 0.f};
      bf16x8 kf0 = ld8(Kb + (size_t)(k0 + lr) * DM + h * 64 + lg * 8);
      bf16x8 kf1 = ld8(Kb + (size_t)(k0 + lr) * DM + h * 64 + 32 + lg * 8);
      acc[h] = mfma16(qf[h][0], kf0, acc[h]);
      acc[h] = mfma16(qf[h][1], kf1, acc[h]);
    }
    bool maskl = (k0 + lr) >= NK;
    #pragma unroll
    for (int g = 0; g < 8; g++) {
      float sv0 = tbl[g], sv1 = tbl[g], sv2 = tbl[g], sv3 = tbl[g];
      #pragma unroll
      for (int h = 0; h < 8; h++) {
        float w = twl[g * 8 + h] * 0.125f;   // fold 1/sqrt(64)
        sv0 += w * acc[h][0]; sv1 += w * acc[h][1];
        sv2 += w * acc[h][2]; sv3 += w * acc[h][3];
      }
      if (maskl) { sv0 = -1e30f; sv1 = -1e30f; sv2 = -1e30f; sv3 = -1e30f; }
      int base = (g * 16 + lg * 4) * S2S + k0 + lr;
      s2[base] = sv0;
      s2[base + S2S] = sv1;
      s2[base + 2 * S2S] = sv2;
      s2[base + 3 * S2S] = sv3;
    }
  }
  __syncthreads();

  // Phase B: full-row softmax (128 rows, 2 threads per row)
  {
    int row = tid >> 1, half = tid & 1;
    const float4* rp4 = (const float4*)(s2 + (size_t)row * S2S + half * 104);
    float m = -1e30f;
    #pragma unroll
    for (int i = 0; i < 26; i++) {
      float4 v = rp4[i];
      m = fmaxf(m, fmaxf(fmaxf(v.x, v.y), fmaxf(v.z, v.w)));
    }
    m = fmaxf(m, __shfl_xor(m, 1));
    float sum = 0.f;
    u16* pw = pb + (size_t)row * NKP + half * 104;
    #pragma unroll
    for (int i = 0; i < 26; i++) {
      float4 v = rp4[i];
      float e0 = __expf(v.x - m), e1 = __expf(v.y - m);
      float e2 = __expf(v.z - m), e3 = __expf(v.w - m);
      sum += (e0 + e1) + (e2 + e3);
      ushort4 o;
      o.x = f2bf(e0); o.y = f2bf(e1); o.z = f2bf(e2); o.w = f2bf(e3);
      *reinterpret_cast<ushort4*>(pw + i * 4) = o;
    }
    sum += __shfl_xor(sum, 1);
    rowsum[row] = sum;
  }
  __syncthreads();

  // Phase C: PV — wave handles heads 2w, 2w+1
  #pragma unroll
  for (int gi = 0; gi < 2; gi++) {
    int g = wv * 2 + gi;
    const u16* pg = pb + (size_t)(g * 16) * NKP;
    f32x4 acc[4] = {};
    for (int kc = 0; kc < 7; kc++) {
      int kof = kc * 32 + lg * 8;
      bool valid = kof < NKP;
      bf16x8 pa = valid ? ld8(pg + (size_t)lr * NKP + kof) : zero8();
      #pragma unroll
      for (int j = 0; j < 4; j++) {
        bf16x8 vb = valid ? ld8(VTb + (size_t)(g * 64 + j * 16 + lr) * NKP + kof) : zero8();
        acc[j] = mfma16(pa, vb, acc[j]);
      }
    }
    #pragma unroll
    for (int j = 0; j < 4; j++) {
      #pragma unroll
      for (int r = 0; r < 4; r++) {
        int q = lg * 4 + r;
        float inv = 1.0f / rowsum[g * 16 + q];
        Oat[((size_t)(b * NQ + q0 + q)) * DM + g * 64 + j * 16 + lr] = f2bf(acc[j][r] * inv);
      }
    }
  }
}

// ---------------- launch ----------------
extern "C" void kernel_launch(void* const* d_in, const int* in_sizes, int n_in,
                              void* d_out, int out_size, void* d_ws, size_t ws_size,
                              hipStream_t stream) {
  const float* queries = (const float*)d_in[0];
  const float* Wq = (const float*)d_in[3];
  const float* bq = (const float*)d_in[4];
  const float* Wk = (const float*)d_in[5];
  const float* bk = (const float*)d_in[6];
  const float* Wv = (const float*)d_in[7];
  const float* bv = (const float*)d_in[8];
  const float* Wo = (const float*)d_in[9];
  const float* bo = (const float*)d_in[10];
  const float* sr_w = (const float*)d_in[11];
  const float* sr_b = (const float*)d_in[12];
  const float* ln_w = (const float*)d_in[13];
  const float* ln_b = (const float*)d_in[14];
  const float* tw = (const float*)d_in[15];
  const float* tb = (const float*)d_in[16];

  char* ws = (char*)d_ws;
  // ws layout (bytes)
  u16* wq_bf = (u16*)(ws + 0);          // 512KB
  u16* wk_bf = (u16*)(ws + 524288);
  u16* wv_bf = (u16*)(ws + 1048576);
  u16* wo_bf = (u16*)(ws + 1572864);
  u16* xln   = (u16*)(ws + 2097152);    // 64*208*512*2 = 13,631,488
  u16* Kbuf  = (u16*)(ws + 15728640);   // 13,631,488
  u16* VTb   = (u16*)(ws + 29360128);   // 13,631,488
  u16* Qbuf  = (u16*)(ws + 42991616);   // 64*784*512*2 = 51,380,224
  u16* Oat   = (u16*)(ws + 94371840);   // 51,380,224  -> end 145,752,064
  if (ws_size < 145752064u) return;     // fail loudly (output stays poisoned)

  const int NW = 262144;  // 512*512
  cvt_kernel<<<256, 256, 0, stream>>>(Wq, wq_bf, NW);
  cvt_kernel<<<256, 256, 0, stream>>>(Wk, wk_bf, NW);
  cvt_kernel<<<256, 256, 0, stream>>>(Wv, wv_bf, NW);
  cvt_kernel<<<256, 256, 0, stream>>>(Wo, wo_bf, NW);

  ln_kernel<<<(NB * NKP) / 4, 256, 0, stream>>>(queries, sr_w, sr_b, ln_w, ln_b, xln);

  // Q = queries @ Wq^T + bq   (fp32 A -> bf16 out), M = 64*784 = 50176
  gemm_kernel<1, 0><<<dim3(4, 392), 256, 0, stream>>>(queries, wq_bf, bq, Qbuf);
  // K = xln @ Wk^T + bk       M = 64*208 = 13312
  gemm_kernel<0, 0><<<dim3(4, 104), 256, 0, stream>>>(xln, wk_bf, bk, Kbuf);
  // V^T = (xln @ Wv^T + bv)^T per batch
  gemm_kernel<0, 2><<<dim3(4, 104), 256, 0, stream>>>(xln, wv_bf, bv, VTb);

  attn_kernel<<<dim3(49, 64), 256, ATTN_SHMEM, stream>>>(Qbuf, Kbuf, VTb, tw, tb, Oat);

  // out = Oat @ Wo^T + bo  (fp32 out)
  gemm_kernel<0, 1><<<dim3(4, 392), 256, 0, stream>>>(Oat, wo_bf, bo, d_out);
}